// Round 1
// baseline (273.630 us; speedup 1.0000x reference)
//
#include <hip/hip_runtime.h>

// QuantizerEMA (B,H,W,D,K)=(32,32,32,64,1024), N=32768. fp32 in / fp32 out.
// R20: k_main rewritten from LDS-tiled 8x8 VALU GEMM to register-resident
// scheme: lane=point (z[64] in VGPRs, loaded once), e wave-uniform via scalar
// loads of a pre-converted fp32 eprime table (written by k_init into ws or the
// EMB out-region, which k_dwf overwrites afterwards). No LDS in the inner
// loop; grid N/64=512 blocks x 512thr -> 2 blocks/CU (16 waves/CU).
// Argmin numerics preserved bitwise vs R17/R19: per-(point,code) sequential
// d=0..63 fp32 FMA chain, dist=(z2+e2)-2*acc, pairwise-8 norms with
// anti-contraction asm barriers, first-index ties (ascending scan + idx
// tiebreak merge). k_init/k_dwf unchanged except eprime store.

typedef unsigned short u16;
typedef u16 us8 __attribute__((ext_vector_type(8)));
typedef float f4 __attribute__((ext_vector_type(4)));

#define WS_FZ    0
#define WS_FE    1
#define WS_FCS   2
#define WS_FEMA  3
#define WS_LOSS  4

__device__ __forceinline__ float b2f(u16 u) {
    union { unsigned int i; float f; } x; x.i = ((unsigned int)u) << 16; return x.f;
}

// ---------- kernel 1: dtype detect + e^2 table + fp32 e copy ----------
__global__ __launch_bounds__(256) void k_init(
    const u16* z, const u16* e, const u16* cs, const u16* ema,
    float* __restrict__ ws, float* __restrict__ esqp,
    float* __restrict__ eprime, int K)
{
    __shared__ int flg[4];
    const int w = threadIdx.x >> 6, l = threadIdx.x & 63;
    const u16* p = (w == 0) ? z : (w == 1) ? e : (w == 2) ? cs : ema;
    int cnt = 0;
    #pragma unroll
    for (int t = 0; t < 4; ++t) {
        unsigned hb = (p[(l * 4 + t) * 2] >> 8) & 0x7F;
        cnt += (hb >= 0x3A && hb <= 0x41) ? 1 : 0;
    }
    #pragma unroll
    for (int off = 32; off; off >>= 1) cnt += __shfl_down(cnt, off);
    if (l == 0) flg[w] = (cnt < 128) ? 1 : 0;
    __syncthreads();
    if (blockIdx.x == 0) {
        if (threadIdx.x < 4) ((int*)ws)[threadIdx.x] = flg[threadIdx.x];
        if (threadIdx.x == 4) ws[WS_LOSS] = 0.0f;
    }
    const int fe = flg[1];
    const int code = blockIdx.x * 256 + threadIdx.x;
    if (code < K) {
        float r[8];
        float* eo = eprime + (size_t)code * 64;
        if (fe) {
            const float* ep = (const float*)e + (size_t)code * 64;
            #pragma unroll
            for (int j = 0; j < 8; ++j) { float v = ep[j]; eo[j] = v;
                float p2 = v * v; asm volatile("" : "+v"(p2)); r[j] = p2; }
            #pragma unroll
            for (int t = 1; t < 8; ++t)
                #pragma unroll
                for (int j = 0; j < 8; ++j) { float v = ep[8 * t + j]; eo[8 * t + j] = v;
                    float p2 = v * v; asm volatile("" : "+v"(p2)); r[j] += p2; }
        } else {
            const u16* ep = e + (size_t)code * 64;
            #pragma unroll
            for (int j = 0; j < 8; ++j) { float v = b2f(ep[j]); eo[j] = v;
                float p2 = v * v; asm volatile("" : "+v"(p2)); r[j] = p2; }
            #pragma unroll
            for (int t = 1; t < 8; ++t)
                #pragma unroll
                for (int j = 0; j < 8; ++j) { float v = b2f(ep[8 * t + j]); eo[8 * t + j] = v;
                    float p2 = v * v; asm volatile("" : "+v"(p2)); r[j] += p2; }
        }
        esqp[code] = ((r[0] + r[1]) + (r[2] + r[3])) + ((r[4] + r[5]) + (r[6] + r[7]));
    }
}

// ---------- kernel 2: distances + argmin + QV/loss epilogue ----------
// 512 blocks x 512 thr. lane=point (64 pts/block), 8 waves split K 8-way.
// z in VGPRs; e via uniform (scalar) loads; no LDS in the hot loop.
__global__ __launch_bounds__(512, 4) void k_main(
    const u16* __restrict__ z,
    const float* __restrict__ esqp, const float* __restrict__ eprime,
    float* __restrict__ ws, float* __restrict__ out,
    int K, int offIdx, long long outSize)
{
    __shared__ float md[8][64];
    __shared__ int   mi[8][64];
    __shared__ int   idx_l[64];

    const int tid  = threadIdx.x;
    const int lane = tid & 63;
    const int w    = tid >> 6;
    const int pbase = blockIdx.x * 64;
    const int p     = pbase + lane;
    const int* wsi = (const int*)ws;
    const int fz = wsi[WS_FZ];

    // ---- z into registers (64 VGPRs), values identical to R19's staging ----
    float zr[64];
    if (fz) {
        const f4* zp = (const f4*)((const float*)z + (size_t)p * 64);
        #pragma unroll
        for (int j = 0; j < 16; ++j) {
            f4 v = zp[j];
            zr[4 * j + 0] = v[0]; zr[4 * j + 1] = v[1];
            zr[4 * j + 2] = v[2]; zr[4 * j + 3] = v[3];
        }
    } else {
        const us8* zp = (const us8*)(z + (size_t)p * 64);
        #pragma unroll
        for (int j = 0; j < 8; ++j) {
            us8 v = zp[j];
            #pragma unroll
            for (int s = 0; s < 8; ++s) zr[8 * j + s] = b2f(v[s]);
        }
    }

    // ---- ||z||^2, np pairwise-8 order, anti-FMA barriers (bitwise R19) ----
    float z2;
    {
        float r[8];
        #pragma unroll
        for (int j = 0; j < 8; ++j) {
            float v = zr[j]; float pq = v * v;
            asm volatile("" : "+v"(pq)); r[j] = pq;
        }
        #pragma unroll
        for (int t = 1; t < 8; ++t)
            #pragma unroll
            for (int j = 0; j < 8; ++j) {
                float v = zr[8 * t + j]; float pq = v * v;
                asm volatile("" : "+v"(pq)); r[j] += pq;
            }
        z2 = ((r[0] + r[1]) + (r[2] + r[3])) + ((r[4] + r[5]) + (r[6] + r[7]));
    }

    // ---- main scan: this wave's K/8 codes, 2-code interleave ----
    const int CPW = K >> 3;                                   // 64..256, even
    const int c0  = __builtin_amdgcn_readfirstlane(w * CPW);  // wave-uniform

    float bestd = INFINITY;
    int   besti = 0;

    for (int c = 0; c < CPW; c += 2) {
        const float* ep0 = eprime + (size_t)(c0 + c) * 64;    // uniform addr
        const float* ep1 = ep0 + 64;
        float a0 = 0.0f, a1 = 0.0f;
        #pragma unroll
        for (int d = 0; d < 64; ++d) {      // sequential d chain per code
            a0 += zr[d] * ep0[d];
            a1 += zr[d] * ep1[d];
        }
        float e20 = esqp[c0 + c];
        float e21 = esqp[c0 + c + 1];
        float d0v = (z2 + e20) - 2.0f * a0;
        float d1v = (z2 + e21) - 2.0f * a1;
        if (d0v < bestd) { bestd = d0v; besti = c0 + c; }      // first-wins
        if (d1v < bestd) { bestd = d1v; besti = c0 + c + 1; }
    }

    // ---- 8-way cross-wave argmin merge (idx tiebreak = global first-min) ----
    md[w][lane] = bestd;
    mi[w][lane] = besti;
    __syncthreads();
    if (tid < 64) {
        float bd = md[0][tid]; int bi = mi[0][tid];
        #pragma unroll
        for (int t = 1; t < 8; ++t) {
            float dv = md[t][tid]; int iv = mi[t][tid];
            if (dv < bd || (dv == bd && iv < bi)) { bd = dv; bi = iv; }
        }
        idx_l[tid] = bi;
        long long oi = (long long)offIdx + pbase + tid;
        if (oi < outSize) out[oi] = (float)bi;
    }
    __syncthreads();

    // ---- epilogue: QV transposed store + loss; wave w owns d in [8w,8w+8) ----
    const int b  = p >> 10;
    const int hw = p & 1023;
    const int kidx = idx_l[lane];
    const float* eq = eprime + (size_t)kidx * 64;
    const long long qbase = (long long)b * 65536 + hw;
    float lsum = 0.0f;
    #pragma unroll
    for (int W = 0; W < 8; ++W) if (w == W) {     // static zr indices per case
        #pragma unroll
        for (int j = 0; j < 8; ++j) {
            const int d = W * 8 + j;
            float zv = zr[d];
            float q  = eq[d];
            float df = zv - q;
            lsum += df * df;
            float qs = zv + (q - zv);
            long long qi = qbase + (long long)d * 1024;
            if (qi < outSize) out[qi] = qs;
        }
    }
    #pragma unroll
    for (int off = 32; off; off >>= 1) lsum += __shfl_down(lsum, off);
    if (lane == 0) atomicAdd(&ws[WS_LOSS], lsum);
}

// ---------- kernel 3: dw scatter + finalize, fused (unchanged) ----------
__global__ __launch_bounds__(512) void k_dwf(
    const u16* __restrict__ z, const float* __restrict__ idxf,
    const u16* __restrict__ cs, const u16* __restrict__ ema,
    float* __restrict__ ws, float* __restrict__ out,
    int K, int N, long long offLoss, long long outSize, float lossScale)
{
    __shared__ int   queue[2048];
    __shared__ int   qcnt;
    __shared__ float cnt[8];
    __shared__ float red[8][512];
    __shared__ float red2[512];

    const int KB = K >> 8;
    const int base = blockIdx.x * KB;
    const int t = threadIdx.x;
    const int w = t >> 6, lane = t & 63;
    const int* wsi = (const int*)ws;
    const int fz = wsi[WS_FZ], fcs = wsi[WS_FCS], fema = wsi[WS_FEMA];

    if (t == 0) qcnt = 0;
    if (t < 8) cnt[t] = 0.0f;
    float acc[8] = {0.f, 0.f, 0.f, 0.f, 0.f, 0.f, 0.f, 0.f};
    __syncthreads();

    const int nseg = (N + 2047) / 2048;
    for (int s = 0; s < nseg; ++s) {
        int i4 = s * 512 + t;
        if (i4 * 4 < N) {
            f4 v = ((const f4*)idxf)[i4];
            #pragma unroll
            for (int j = 0; j < 4; ++j) {
                int k = (int)v[j];
                if (k >= base && k < base + KB) {
                    int qi = atomicAdd(&qcnt, 1);
                    queue[qi] = ((i4 * 4 + j) << 3) | (k - base);
                    atomicAdd(&cnt[k - base], 1.0f);
                }
            }
        }
        __syncthreads();
        const int n = qcnt;
        for (int ent = w; ent < n; ent += 8) {
            int q = queue[ent];
            int p = q >> 3, kl = q & 7;
            float v = fz ? ((const float*)z)[(size_t)p * 64 + lane]
                         : b2f(z[(size_t)p * 64 + lane]);
            #pragma unroll
            for (int c = 0; c < 8; ++c) acc[c] += (c == kl) ? v : 0.0f;
        }
        __syncthreads();
        if (t == 0) qcnt = 0;
        __syncthreads();
    }

    #pragma unroll
    for (int c = 0; c < 8; ++c)
        if (c < KB) red[w][c * 64 + lane] = acc[c];

    float partial = 0.f;
    for (int k0 = 0; k0 < K; k0 += 512) {
        int kk = k0 + t;
        if (kk < K) partial += fcs ? ((const float*)cs)[kk] : b2f(cs[kk]);
    }
    red2[t] = partial;
    __syncthreads();
    for (int s = 256; s; s >>= 1) {
        if (t < s) red2[t] += red2[t + s];
        __syncthreads();
    }
    const float n = 0.99f * red2[0] + 0.01f * (float)N;
    const float keps = (float)K * 1e-5f;

    const long long offEmb = offLoss + 1;
    const long long offCl  = offEmb + (long long)K * 64;
    const long long offEma = offCl + K;

    if (t < KB * 64) {
        int kl = t >> 6, d = t & 63;
        int kk = base + kl;
        float dw = 0.f;
        #pragma unroll
        for (int ww = 0; ww < 8; ++ww) dw += red[ww][kl * 64 + d];
        float c = (fcs ? ((const float*)cs)[kk] : b2f(cs[kk])) * 0.99f + cnt[kl] * 0.01f;
        float sm = (c + 1e-5f) / (n + keps) * n;
        long long i = (long long)kk * 64 + d;
        float ev = fema ? ((const float*)ema)[i] : b2f(ema[i]);
        float ne = ev * 0.99f + dw * 0.01f;
        if (offEma + i < outSize) out[offEma + i] = ne;
        if (offEmb + i < outSize) out[offEmb + i] = ne / sm;
        if (d == 0 && offCl + kk < outSize) out[offCl + kk] = sm;
    }
    if (blockIdx.x == 0 && t == 0 && offLoss < outSize)
        out[offLoss] = 0.25f * (ws[WS_LOSS] * lossScale);
}

extern "C" void kernel_launch(void* const* d_in, const int* in_sizes, int n_in,
                              void* d_out, int out_size, void* d_ws, size_t ws_size,
                              hipStream_t stream) {
    long long sz[4] = {0, 0, 0, 0};
    for (int i = 0; i < n_in && i < 4; ++i) sz[i] = in_sizes[i];
    int icl = 0, iz = 0;
    for (int i = 1; i < 4; ++i) { if (sz[i] < sz[icl]) icl = i; if (sz[i] > sz[iz]) iz = i; }
    int ip[2], np = 0;
    for (int i = 0; i < 4; ++i) if (i != icl && i != iz && np < 2) ip[np++] = i;
    long long K = sz[icl], KD = (np == 2) ? sz[ip[0]] : 0;
    int derivOK = (n_in == 4 && np == 2 && icl != iz && sz[ip[0]] == sz[ip[1]] &&
                   K > 0 && KD % K == 0);
    long long D = derivOK ? KD / K : 64;
    long long N = (derivOK && D > 0 && sz[iz] % D == 0) ? sz[iz] / D : 32768;
    int ie, iema;
    if (!derivOK) { iz = 0; ie = 1; icl = 2; iema = 3; N = 32768; K = 1024; D = 64; }
    else if (icl > ip[0] && icl < ip[1]) { ie = ip[0]; iema = ip[1]; }  // dict order
    else { iema = ip[0]; ie = ip[1]; }                                  // sorted order

    int fastOK = (D == 64) && (N % 1024 == 0) && (K % 256 == 0) &&
                 (K >= 512) && (K <= 2048);
    if (!fastOK) { N = 32768; K = 1024; }

    long long offIdx = N * 64, offLoss = offIdx + N;

    float* out = (float*)d_out;
    float* ws = (float*)d_ws;
    float* esqp = ((long long)ws_size >= (8 + K) * 4) ? (ws + 8)
                 : (out + offLoss + 1 + K * 64);              // CL region
    float* eprime = ((long long)ws_size >= (8 + K + K * 64) * 4) ? (ws + 8 + K)
                 : (out + offLoss + 1);                        // EMB region (k_dwf overwrites after)

    const u16* z   = (const u16*)d_in[iz];
    const u16* e   = (const u16*)d_in[ie];
    const u16* cs  = (const u16*)d_in[icl];
    const u16* ema = (const u16*)d_in[iema];

    float lossScale = (float)(1.0 / (double)(N * 64));

    k_init<<<(int)((K + 255) / 256), 256, 0, stream>>>(z, e, cs, ema, ws, esqp, eprime, (int)K);
    k_main<<<(int)(N / 64), 512, 0, stream>>>(z, esqp, eprime, ws, out,
                                              (int)K, (int)offIdx, (long long)out_size);
    k_dwf<<<256, 512, 0, stream>>>(z, out + offIdx, cs, ema, ws, out,
                                   (int)K, (int)N, offLoss,
                                   (long long)out_size, lossScale);
}